// Round 4
// baseline (137.236 us; speedup 1.0000x reference)
//
#include <hip/hip_runtime.h>
#include <hip/hip_bf16.h>
#include <stdint.h>

#define K_DIM 20000
#define N_DIM 512
#define M_DIM 2048

#define BM 128
#define BN 128
#define BK 32              // 32 bf16 = 64 B per LDS row = 4 x 16B chunks
#define NSTEPS 625         // K_DIM / BK (exact)
#define SPLITS 20          // 64 tiles * 20 = 1280 blocks = exactly 5 blocks/CU (LDS-capped)
#define GEMM_THREADS 256

typedef __bf16 bf16_t;
typedef bf16_t  bf16x8 __attribute__((ext_vector_type(8)));
typedef float   f32x4  __attribute__((ext_vector_type(4)));
typedef uint32_t u32x2 __attribute__((ext_vector_type(2)));
typedef uint32_t u32x4 __attribute__((ext_vector_type(4)));

__device__ __forceinline__ uint32_t pack_bf16x2(float a, float b) {
  uint32_t ua = (uint32_t)__builtin_bit_cast(uint16_t, (bf16_t)a);
  uint32_t ub = (uint32_t)__builtin_bit_cast(uint16_t, (bf16_t)b);
  return ua | (ub << 16);
}

// async global->LDS, 16B per lane. LDS dest must be wave-uniform base
// (HW writes base + lane*16 linearly); global src is per-lane.
__device__ __forceinline__ void gload16(const uint16_t* g, uint16_t* l) {
  __builtin_amdgcn_global_load_lds(
      (const __attribute__((address_space(1))) void*)g,
      (__attribute__((address_space(3))) void*)l, 16, 0, 0);
}

// ---------------------------------------------------------------------------
// Kernel 0: E (K x N fp32, row-major) -> Bt (N x K bf16, row-major)
// ---------------------------------------------------------------------------
__global__ __launch_bounds__(256)
void bt_transpose_kernel(const float* __restrict__ B, uint16_t* __restrict__ Bt) {
  const int kb = blockIdx.x;      // 0..624
  const int nb = blockIdx.y;      // 0..7
  const int t  = threadIdx.x;
  const int rn = t >> 2;          // 0..63 local n
  const int kc = t & 3;           // 0..3  (8 k each)
  const int n  = nb * 64 + rn;
  const int kk = kb * 32 + kc * 8;

  float v[8];
#pragma unroll
  for (int j = 0; j < 8; ++j)
    v[j] = B[(size_t)(kk + j) * N_DIM + n];

  u32x4 q;
#pragma unroll
  for (int j = 0; j < 4; ++j)
    q[j] = pack_bf16x2(v[2 * j], v[2 * j + 1]);

  *reinterpret_cast<u32x4*>(&Bt[(size_t)n * K_DIM + kk]) = q;
}

// ---------------------------------------------------------------------------
// Kernel 1: out[m][n] = bias[n]   (accumulation target for split-K atomics)
// ---------------------------------------------------------------------------
__global__ __launch_bounds__(256)
void init_out_kernel(const float* __restrict__ bias, float* __restrict__ out) {
  const int i = blockIdx.x * 256 + threadIdx.x;
  out[i] = bias[i & (N_DIM - 1)];
}

// ---------------------------------------------------------------------------
// Kernel 2: split-K bf16 MFMA GEMM, 128x128 tile, 4 waves (2x2), BK=32.
// A: fp32 global -> reg convert -> swizzled ds_write (double-buffered 8 KB ea)
// B: global_load_lds 16B, pre-swizzled per-lane source, linear LDS dest
//    (double-buffered 8 KB ea). Total LDS 32 KB -> 5 blocks/CU at grid 1280.
// LDS swizzle: 16B chunk c at row r lives at phys chunk c ^ ((r>>1)&3);
// verified conflict-free for b128 frag reads and staging writes (R3: BC=0).
// NOTE: no __launch_bounds__ min-waves — R2 showed it forces spill (WRITE 754MB).
// ---------------------------------------------------------------------------
__global__ __launch_bounds__(GEMM_THREADS)
void gemm_split_kernel(const float* __restrict__ X,
                       const uint16_t* __restrict__ Bt,
                       float* __restrict__ out) {
  __shared__ __align__(16) uint16_t Al[2][BM * 32];   // 8 KB each
  __shared__ __align__(16) uint16_t Bl[2][BN * 32];   // 8 KB each

  const int bid  = blockIdx.x;
  const int s    = bid >> 6;       // K-split 0..SPLITS-1
  const int tile = bid & 63;
  const int mt   = tile & 15;
  const int nt   = tile >> 4;      // 0..3
  const int m0 = mt * BM;
  const int n0 = nt * BN;
  const int step0 = (s * NSTEPS) / SPLITS;
  const int step1 = ((s + 1) * NSTEPS) / SPLITS;
  const int nsteps = step1 - step0;   // 31 or 32

  const int t    = threadIdx.x;
  const int wid  = t >> 6;
  const int lane = t & 63;
  const int wr  = (wid >> 1) * 64;  // wave row offset in tile
  const int wc  = (wid & 1) * 64;   // wave col offset in tile
  const int l15 = lane & 15;
  const int l16 = lane >> 4;        // 0..3

  // --- A staging decomposition: 4 passes of 32 rows, 8 lanes x 16B per row
  const int arow = t >> 3;          // 0..31
  const int af4  = t & 7;           // fp32x4 chunk in row (8 x 16B fp32 = 128B)
  const int aswz = (arow >> 1) & 3; // invariant under row+32p
  const int aoff = ((af4 >> 1) ^ aswz) * 8 + (af4 & 1) * 4;  // ushort offset in row
  const float* __restrict__ xptr = X + (size_t)(m0 + arow) * K_DIM + step0 * BK + af4 * 4;

  // --- B gload_lds decomposition: wave w, call q covers rows w*32+q*16..+16
  const int brow0 = wid * 32 + (lane >> 2);        // rows for q=0 (q=1: +16)
  const int bch   = (lane & 3) ^ ((brow0 >> 1) & 3); // src chunk (swizzle inv.)
  const uint16_t* __restrict__ bsrc0 =
      Bt + (size_t)(n0 + brow0) * K_DIM + step0 * BK + bch * 8;
  const uint16_t* __restrict__ bsrc1 = bsrc0 + (size_t)16 * K_DIM;
  const int bdst0 = wid * 1024;     // ushort offset of wave's q=0 chunk
  const int bdst1 = bdst0 + 512;

  // --- frag read offsets (chunk swizzle is mf/nf-invariant)
  const int rsw   = ((l15 >> 1) & 3);
  const int fchunk = ((l16 ^ rsw) << 3);

  f32x4 acc[4][4] = {};

  // prologue: stage step0 into buffer 0
  gload16(bsrc0, &Bl[0][bdst0]);
  gload16(bsrc1, &Bl[0][bdst1]);
#pragma unroll
  for (int p = 0; p < 4; ++p) {
    f32x4 v = *reinterpret_cast<const f32x4*>(xptr + (size_t)p * 32 * K_DIM);
    u32x2 w;
    w[0] = pack_bf16x2(v[0], v[1]);
    w[1] = pack_bf16x2(v[2], v[3]);
    *reinterpret_cast<u32x2*>(&Al[0][(arow + p * 32) * 32 + aoff]) = w;
  }
  __syncthreads();

  int buf = 0;
  for (int i = 0; i < nsteps; ++i) {
    const bool have = (i + 1 < nsteps);
    const int nbuf = buf ^ 1;
    f32x4 av[4];
    if (have) {
      const int koff = (i + 1) * BK;
      // B: async direct-to-LDS (in flight across the MFMA block)
      gload16(bsrc0 + koff, &Bl[nbuf][bdst0]);
      gload16(bsrc1 + koff, &Bl[nbuf][bdst1]);
      // A: issue fp32 loads early
#pragma unroll
      for (int p = 0; p < 4; ++p)
        av[p] = *reinterpret_cast<const f32x4*>(xptr + (size_t)p * 32 * K_DIM + koff);
    }

    // compute current buffer
    bf16x8 afr[4], bfr[4];
#pragma unroll
    for (int mf = 0; mf < 4; ++mf)
      afr[mf] = *reinterpret_cast<const bf16x8*>(&Al[buf][(wr + mf * 16 + l15) * 32 + fchunk]);
#pragma unroll
    for (int nf = 0; nf < 4; ++nf)
      bfr[nf] = *reinterpret_cast<const bf16x8*>(&Bl[buf][(wc + nf * 16 + l15) * 32 + fchunk]);
#pragma unroll
    for (int mf = 0; mf < 4; ++mf)
#pragma unroll
      for (int nf = 0; nf < 4; ++nf)
        acc[mf][nf] = __builtin_amdgcn_mfma_f32_16x16x32_bf16(afr[mf], bfr[nf], acc[mf][nf], 0, 0, 0);

    // A: convert + swizzled write into the other buffer
    if (have) {
#pragma unroll
      for (int p = 0; p < 4; ++p) {
        u32x2 w;
        w[0] = pack_bf16x2(av[p][0], av[p][1]);
        w[1] = pack_bf16x2(av[p][2], av[p][3]);
        *reinterpret_cast<u32x2*>(&Al[nbuf][(arow + p * 32) * 32 + aoff]) = w;
      }
    }
    __syncthreads();   // drains vmcnt(0) (B gload_lds) + lgkmcnt (A writes)
    buf ^= 1;
  }

  // epilogue: scaled atomic accumulation (C/D: col = lane&15, row = (lane>>4)*4 + j)
  const float scale = 1.0f / (float)K_DIM;
#pragma unroll
  for (int mf = 0; mf < 4; ++mf) {
#pragma unroll
    for (int nf = 0; nf < 4; ++nf) {
      const int row = m0 + wr + mf * 16 + l16 * 4;
      const int col = n0 + wc + nf * 16 + l15;
#pragma unroll
      for (int j = 0; j < 4; ++j)
        atomicAdd(&out[(size_t)(row + j) * N_DIM + col], acc[mf][nf][j] * scale);
    }
  }
}

// ---------------------------------------------------------------------------
extern "C" void kernel_launch(void* const* d_in, const int* in_sizes, int n_in,
                              void* d_out, int out_size, void* d_ws, size_t ws_size,
                              hipStream_t stream) {
  (void)in_sizes; (void)n_in; (void)out_size; (void)ws_size;
  const float* x    = (const float*)d_in[0];
  const float* emb  = (const float*)d_in[1];
  const float* bias = (const float*)d_in[2];
  float*    out = (float*)d_out;
  uint16_t* bt  = (uint16_t*)d_ws;   // 512*20000*2 = 20.48 MB

  bt_transpose_kernel<<<dim3(K_DIM / 32, N_DIM / 64), 256, 0, stream>>>(emb, bt);
  init_out_kernel<<<(M_DIM * N_DIM) / 256, 256, 0, stream>>>(bias, out);
  gemm_split_kernel<<<64 * SPLITS, GEMM_THREADS, 0, stream>>>(x, bt, out);
}

// Round 5
// 135.832 us; speedup vs baseline: 1.0103x; 1.0103x over previous
//
#include <hip/hip_runtime.h>
#include <hip/hip_bf16.h>
#include <stdint.h>

#define K_DIM 20000
#define N_DIM 512
#define M_DIM 2048

#define BM 64
#define BN 512             // full N: x read exactly once at every cache level
#define BK 32              // 32 bf16 = 64 B per LDS row = 4 x 16B chunks
#define NSTEPS 625         // K_DIM / BK (exact)
#define SPLITS 8           // 32 m-tiles * 8 = 256 blocks = 1 block/CU
#define GEMM_THREADS 512   // 8 waves, each owns a 64x64 output sub-tile

typedef __bf16 bf16_t;
typedef bf16_t  bf16x8 __attribute__((ext_vector_type(8)));
typedef float   f32x4  __attribute__((ext_vector_type(4)));
typedef uint32_t u32x2 __attribute__((ext_vector_type(2)));
typedef uint32_t u32x4 __attribute__((ext_vector_type(4)));

__device__ __forceinline__ uint32_t pack_bf16x2(float a, float b) {
  uint32_t ua = (uint32_t)__builtin_bit_cast(uint16_t, (bf16_t)a);
  uint32_t ub = (uint32_t)__builtin_bit_cast(uint16_t, (bf16_t)b);
  return ua | (ub << 16);
}

// ---------------------------------------------------------------------------
// Kernel 0: E (K x N fp32, row-major) -> Bt (N x K bf16, row-major)
// ---------------------------------------------------------------------------
__global__ __launch_bounds__(256)
void bt_transpose_kernel(const float* __restrict__ B, uint16_t* __restrict__ Bt) {
  const int kb = blockIdx.x;      // 0..624
  const int nb = blockIdx.y;      // 0..7
  const int t  = threadIdx.x;
  const int rn = t >> 2;          // 0..63 local n
  const int kc = t & 3;           // 0..3  (8 k each)
  const int n  = nb * 64 + rn;
  const int kk = kb * 32 + kc * 8;

  float v[8];
#pragma unroll
  for (int j = 0; j < 8; ++j)
    v[j] = B[(size_t)(kk + j) * N_DIM + n];

  u32x4 q;
#pragma unroll
  for (int j = 0; j < 4; ++j)
    q[j] = pack_bf16x2(v[2 * j], v[2 * j + 1]);

  *reinterpret_cast<u32x4*>(&Bt[(size_t)n * K_DIM + kk]) = q;
}

// ---------------------------------------------------------------------------
// Kernel 1: out[m][n] = bias[n]   (accumulation target for split-K atomics)
// ---------------------------------------------------------------------------
__global__ __launch_bounds__(256)
void init_out_kernel(const float* __restrict__ bias, float* __restrict__ out) {
  const int i = blockIdx.x * 256 + threadIdx.x;
  out[i] = bias[i & (N_DIM - 1)];
}

// ---------------------------------------------------------------------------
// Kernel 2: split-K bf16 MFMA GEMM, 64x512 tile (full-N), 8 waves (1x8),
// wave sub-tile 64x64 = 4x4 frags of 16x16x32, BK=32.
//   A (x fp32): global -> reg -> pack bf16 -> swizzled ds_write, dbuf 4KB ea.
//       8x intra-block reuse (all waves read the same A rows).
//   B (Bt bf16): DIRECT global -> register fragments, no LDS. Each l16-group
//       of 4 lanes consumes one 64B line of a Bt row; Bt k-slice (2.5 MB)
//       is L2-resident on its XCD (s = bid&7 -> all same-s blocks on one XCD).
// grid = 256 blocks (1/CU), 512 threads.
// ---------------------------------------------------------------------------
__global__ __launch_bounds__(GEMM_THREADS)
void gemm_split_kernel(const float* __restrict__ X,
                       const uint16_t* __restrict__ Bt,
                       float* __restrict__ out) {
  __shared__ __align__(16) uint16_t Al[2][BM * 32];   // 4 KB each

  const int bid = blockIdx.x;
  const int s   = bid & 7;         // K-split -> XCD = bid%8 = s (L2 locality)
  const int mt  = bid >> 3;        // 0..31
  const int m0  = mt * BM;
  const int step0 = (s * NSTEPS) / SPLITS;
  const int step1 = ((s + 1) * NSTEPS) / SPLITS;
  const int nsteps = step1 - step0;   // 78 or 79

  const int t    = threadIdx.x;
  const int wid  = t >> 6;          // 0..7
  const int lane = t & 63;
  const int wc   = wid * 64;        // wave col offset (n)
  const int l15  = lane & 15;
  const int l16  = lane >> 4;       // 0..3

  // --- A staging: 64 rows x 8 chunks of f32x4; one 16B fp32 load per thread
  const int arow = t >> 3;          // 0..63
  const int af4  = t & 7;           // f32x4 chunk in row
  const int aswz = (arow >> 1) & 3;
  const int aoff = (((af4 >> 1) ^ aswz) << 3) + (af4 & 1) * 4;  // ushort offset
  const float* __restrict__ xptr =
      X + (size_t)(m0 + arow) * K_DIM + step0 * BK + af4 * 4;

  // --- A frag read offsets (swizzle is mf-invariant: (mf*16+l15)>>1 & 3 == (l15>>1)&3)
  const int fchunk = ((l16 ^ ((l15 >> 1) & 3)) << 3);

  // --- B direct-load row pointers: frag nf reads Bt[wc + nf*16 + l15][k0 + l16*8 ..]
  const uint16_t* __restrict__ b0 =
      Bt + (size_t)(wc + l15) * K_DIM + step0 * BK + l16 * 8;
  const uint16_t* __restrict__ b1 = b0 + (size_t)16 * K_DIM;
  const uint16_t* __restrict__ b2 = b0 + (size_t)32 * K_DIM;
  const uint16_t* __restrict__ b3 = b0 + (size_t)48 * K_DIM;

  f32x4 acc[4][4] = {};

  // prologue: stage A step0 into buffer 0; load B step0 fragments
  {
    f32x4 v = *reinterpret_cast<const f32x4*>(xptr);
    u32x2 w;
    w[0] = pack_bf16x2(v[0], v[1]);
    w[1] = pack_bf16x2(v[2], v[3]);
    *reinterpret_cast<u32x2*>(&Al[0][arow * 32 + aoff]) = w;
  }
  bf16x8 bcur0 = *reinterpret_cast<const bf16x8*>(b0);
  bf16x8 bcur1 = *reinterpret_cast<const bf16x8*>(b1);
  bf16x8 bcur2 = *reinterpret_cast<const bf16x8*>(b2);
  bf16x8 bcur3 = *reinterpret_cast<const bf16x8*>(b3);
  __syncthreads();

  int buf = 0;
  for (int i = 0; i < nsteps; ++i) {
    const bool have = (i + 1 < nsteps);
    const int nbuf = buf ^ 1;
    const int koff = (i + 1) * BK;

    // issue next-step loads early: B->regs (L2, hidden under MFMA),
    // A fp32 (HBM, mostly hidden under MFMA)
    f32x4 av;
    bf16x8 bn0, bn1, bn2, bn3;
    if (have) {
      bn0 = *reinterpret_cast<const bf16x8*>(b0 + koff);
      bn1 = *reinterpret_cast<const bf16x8*>(b1 + koff);
      bn2 = *reinterpret_cast<const bf16x8*>(b2 + koff);
      bn3 = *reinterpret_cast<const bf16x8*>(b3 + koff);
      av  = *reinterpret_cast<const f32x4*>(xptr + koff);
    }

    // A fragments from LDS (same rows for all 8 waves)
    bf16x8 afr[4];
#pragma unroll
    for (int mf = 0; mf < 4; ++mf)
      afr[mf] = *reinterpret_cast<const bf16x8*>(&Al[buf][(mf * 16 + l15) * 32 + fchunk]);

#pragma unroll
    for (int mf = 0; mf < 4; ++mf) {
      acc[mf][0] = __builtin_amdgcn_mfma_f32_16x16x32_bf16(afr[mf], bcur0, acc[mf][0], 0, 0, 0);
      acc[mf][1] = __builtin_amdgcn_mfma_f32_16x16x32_bf16(afr[mf], bcur1, acc[mf][1], 0, 0, 0);
      acc[mf][2] = __builtin_amdgcn_mfma_f32_16x16x32_bf16(afr[mf], bcur2, acc[mf][2], 0, 0, 0);
      acc[mf][3] = __builtin_amdgcn_mfma_f32_16x16x32_bf16(afr[mf], bcur3, acc[mf][3], 0, 0, 0);
    }

    // A: pack + swizzled write into the other buffer
    if (have) {
      u32x2 w;
      w[0] = pack_bf16x2(av[0], av[1]);
      w[1] = pack_bf16x2(av[2], av[3]);
      *reinterpret_cast<u32x2*>(&Al[nbuf][arow * 32 + aoff]) = w;
      bcur0 = bn0; bcur1 = bn1; bcur2 = bn2; bcur3 = bn3;
    }
    __syncthreads();
    buf ^= 1;
  }

  // epilogue: scaled atomic accumulation (C/D: col = lane&15, row = (lane>>4)*4 + j)
  const float scale = 1.0f / (float)K_DIM;
#pragma unroll
  for (int mf = 0; mf < 4; ++mf) {
#pragma unroll
    for (int nf = 0; nf < 4; ++nf) {
      const int row = m0 + mf * 16 + l16 * 4;
      const int col = wc + nf * 16 + l15;
#pragma unroll
      for (int j = 0; j < 4; ++j)
        atomicAdd(&out[(size_t)(row + j) * N_DIM + col], acc[mf][nf][j] * scale);
    }
  }
}

// ---------------------------------------------------------------------------
extern "C" void kernel_launch(void* const* d_in, const int* in_sizes, int n_in,
                              void* d_out, int out_size, void* d_ws, size_t ws_size,
                              hipStream_t stream) {
  (void)in_sizes; (void)n_in; (void)out_size; (void)ws_size;
  const float* x    = (const float*)d_in[0];
  const float* emb  = (const float*)d_in[1];
  const float* bias = (const float*)d_in[2];
  float*    out = (float*)d_out;
  uint16_t* bt  = (uint16_t*)d_ws;   // 512*20000*2 = 20.48 MB

  bt_transpose_kernel<<<dim3(K_DIM / 32, N_DIM / 64), 256, 0, stream>>>(emb, bt);
  init_out_kernel<<<(M_DIM * N_DIM) / 256, 256, 0, stream>>>(bias, out);
  gemm_split_kernel<<<(M_DIM / BM) * SPLITS, GEMM_THREADS, 0, stream>>>(x, bt, out);
}

// Round 6
// 109.328 us; speedup vs baseline: 1.2553x; 1.2424x over previous
//
#include <hip/hip_runtime.h>
#include <hip/hip_bf16.h>
#include <stdint.h>

#define K_DIM 20000
#define N_DIM 512
#define M_DIM 2048

#define BM 128
#define BN 128
#define BK 32              // 32 bf16 = 64 B per LDS row = 4 x 16B chunks
#define NSTEPS 625         // K_DIM / BK (exact)
#define SPLITS 12          // 64 tiles * 12 = 768 blocks = 3 blocks/CU
#define GRID (64 * SPLITS)
#define GEMM_THREADS 256

typedef __bf16 bf16_t;
typedef bf16_t  bf16x8 __attribute__((ext_vector_type(8)));
typedef float   f32x4  __attribute__((ext_vector_type(4)));
typedef uint32_t u32x2 __attribute__((ext_vector_type(2)));
typedef uint32_t u32x4 __attribute__((ext_vector_type(4)));

__device__ __forceinline__ uint32_t pack_bf16x2(float a, float b) {
  uint32_t ua = (uint32_t)__builtin_bit_cast(uint16_t, (bf16_t)a);
  uint32_t ub = (uint32_t)__builtin_bit_cast(uint16_t, (bf16_t)b);
  return ua | (ub << 16);
}

// async global->LDS, 16B per lane. LDS dest is wave-uniform base + lane*16
// (linear); global src is per-lane (pre-swizzled to match swizzled reads).
__device__ __forceinline__ void gload16(const uint16_t* g, uint16_t* l) {
  __builtin_amdgcn_global_load_lds(
      (const __attribute__((address_space(1))) void*)g,
      (__attribute__((address_space(3))) void*)l, 16, 0, 0);
}

// ---------------------------------------------------------------------------
// Kernel 0: E (K x N fp32, row-major) -> Bt (N x K bf16, row-major)
// ---------------------------------------------------------------------------
__global__ __launch_bounds__(256)
void bt_transpose_kernel(const float* __restrict__ B, uint16_t* __restrict__ Bt) {
  const int kb = blockIdx.x;      // 0..624
  const int nb = blockIdx.y;      // 0..7
  const int t  = threadIdx.x;
  const int rn = t >> 2;          // 0..63 local n
  const int kc = t & 3;           // 0..3  (8 k each)
  const int n  = nb * 64 + rn;
  const int kk = kb * 32 + kc * 8;

  float v[8];
#pragma unroll
  for (int j = 0; j < 8; ++j)
    v[j] = B[(size_t)(kk + j) * N_DIM + n];

  u32x4 q;
#pragma unroll
  for (int j = 0; j < 4; ++j)
    q[j] = pack_bf16x2(v[2 * j], v[2 * j + 1]);

  *reinterpret_cast<u32x4*>(&Bt[(size_t)n * K_DIM + kk]) = q;
}

// ---------------------------------------------------------------------------
// Kernel 1: out[m][n] = bias[n]   (accumulation target for split-K atomics)
// ---------------------------------------------------------------------------
__global__ __launch_bounds__(256)
void init_out_kernel(const float* __restrict__ bias, float* __restrict__ out) {
  const int i = blockIdx.x * 256 + threadIdx.x;
  out[i] = bias[i & (N_DIM - 1)];
}

// ---------------------------------------------------------------------------
// Kernel 2: split-K bf16 MFMA GEMM, 128x128 tile, 4 waves (2x2), BK=32.
// Pipeline (counted-vmcnt, never vmcnt(0) at steady-state barriers):
//   per step i: issue B gload_lds(i+1) [2 ops] -> sched_barrier ->
//               issue A loads(i+2) [4 ops] -> frag reads + 16 MFMA ->
//               pack A(i+1) (regs from step i-1) -> ds_write ->
//               s_waitcnt vmcnt(4) lgkmcnt(0); s_barrier
//   => A HBM latency spans 2 steps; A(i+2) loads fly ACROSS the barrier.
// XCD-chunked bid swizzle: 16 m-blocks sharing (s,nt) Bt slice on one XCD.
// ---------------------------------------------------------------------------
__global__ __launch_bounds__(GEMM_THREADS)
void gemm_split_kernel(const float* __restrict__ X,
                       const uint16_t* __restrict__ Bt,
                       float* __restrict__ out) {
  __shared__ __align__(16) uint16_t Al[2][BM * 32];   // 8 KB each
  __shared__ __align__(16) uint16_t Bl[2][BN * 32];   // 8 KB each

  // XCD-chunk swizzle (bijective, GRID % 8 == 0): phys p%8 = XCD; give each
  // XCD a contiguous logical range so 16-block (s,nt) chunks co-locate.
  const int phys = blockIdx.x;
  const int bid  = (phys & 7) * (GRID / 8) + (phys >> 3);
  const int mt    = bid & 15;         // m-tile 0..15
  const int chunk = bid >> 4;         // 0..(4*SPLITS-1)
  const int nt    = chunk & 3;        // n-tile 0..3
  const int s     = chunk >> 2;       // K-split 0..SPLITS-1
  const int m0 = mt * BM;
  const int n0 = nt * BN;
  const int step0 = (s * NSTEPS) / SPLITS;
  const int step1 = ((s + 1) * NSTEPS) / SPLITS;
  const int nsteps = step1 - step0;   // 52 or 53

  const int t    = threadIdx.x;
  const int wid  = t >> 6;
  const int lane = t & 63;
  const int wr  = (wid >> 1) * 64;  // wave row offset in tile
  const int wc  = (wid & 1) * 64;   // wave col offset in tile
  const int l15 = lane & 15;
  const int l16 = lane >> 4;        // 0..3

  // --- A staging decomposition: 4 passes of 32 rows, 8 lanes x 16B per row
  const int arow = t >> 3;          // 0..31
  const int af4  = t & 7;           // fp32x4 chunk in row
  const int aswz = (arow >> 1) & 3; // invariant under row+32p
  const int aoff = ((af4 >> 1) ^ aswz) * 8 + (af4 & 1) * 4;  // ushort offset
  const float* __restrict__ xptr = X + (size_t)(m0 + arow) * K_DIM + step0 * BK + af4 * 4;

  // --- B gload_lds decomposition: wave w, call q covers rows w*32+q*16..+16
  const int brow0 = wid * 32 + (lane >> 2);          // rows for q=0 (q=1: +16)
  const int bch   = (lane & 3) ^ ((brow0 >> 1) & 3); // src chunk (swizzle inv.)
  const uint16_t* __restrict__ bsrc0 =
      Bt + (size_t)(n0 + brow0) * K_DIM + step0 * BK + bch * 8;
  const uint16_t* __restrict__ bsrc1 = bsrc0 + (size_t)16 * K_DIM;
  const int bdst0 = wid * 1024;     // ushort offset of wave's q=0 chunk
  const int bdst1 = bdst0 + 512;

  // --- frag read offsets (chunk swizzle is mf/nf-invariant)
  const int fchunk = ((l16 ^ ((l15 >> 1) & 3)) << 3);

  f32x4 acc[4][4] = {};
  f32x4 a1[4];   // A data for step i+1 (loaded at step i-1)

  // ---- prologue: B(0) gload -> buf0; A(0) load+pack -> buf0; A(1) -> a1
  gload16(bsrc0, &Bl[0][bdst0]);
  gload16(bsrc1, &Bl[0][bdst1]);
  __builtin_amdgcn_sched_barrier(0);
  f32x4 a0[4];
#pragma unroll
  for (int p = 0; p < 4; ++p)
    a0[p] = *reinterpret_cast<const f32x4*>(xptr + (size_t)p * 32 * K_DIM);
#pragma unroll
  for (int p = 0; p < 4; ++p)
    a1[p] = *reinterpret_cast<const f32x4*>(xptr + (size_t)p * 32 * K_DIM + BK);
#pragma unroll
  for (int p = 0; p < 4; ++p) {
    u32x2 w;
    w[0] = pack_bf16x2(a0[p][0], a0[p][1]);
    w[1] = pack_bf16x2(a0[p][2], a0[p][3]);
    *reinterpret_cast<u32x2*>(&Al[0][(arow + p * 32) * 32 + aoff]) = w;
  }
  asm volatile("s_waitcnt vmcnt(4) lgkmcnt(0)" ::: "memory");  // a1 stays in flight
  __builtin_amdgcn_s_barrier();
  __builtin_amdgcn_sched_barrier(0);

  int buf = 0;
  for (int i = 0; i < nsteps; ++i) {
    const int nbuf = buf ^ 1;
    const bool have1 = (i + 1 < nsteps);
    const bool have2 = (i + 2 < nsteps);

    // 1) issue B(i+1) gload_lds (oldest vmem this step)
    if (have1) {
      const int koff = (i + 1) * BK;
      gload16(bsrc0 + koff, &Bl[nbuf][bdst0]);
      gload16(bsrc1 + koff, &Bl[nbuf][bdst1]);
    }
    __builtin_amdgcn_sched_barrier(0);   // pin: B issued before A loads

    // 2) issue A(i+2) loads (newest; allowed to stay in flight across barrier)
    f32x4 a2[4];
    if (have2) {
      const int koff = (i + 2) * BK;
#pragma unroll
      for (int p = 0; p < 4; ++p)
        a2[p] = *reinterpret_cast<const f32x4*>(xptr + (size_t)p * 32 * K_DIM + koff);
    }

    // 3) compute current buffer
    bf16x8 afr[4], bfr[4];
#pragma unroll
    for (int mf = 0; mf < 4; ++mf)
      afr[mf] = *reinterpret_cast<const bf16x8*>(&Al[buf][(wr + mf * 16 + l15) * 32 + fchunk]);
#pragma unroll
    for (int nf = 0; nf < 4; ++nf)
      bfr[nf] = *reinterpret_cast<const bf16x8*>(&Bl[buf][(wc + nf * 16 + l15) * 32 + fchunk]);
#pragma unroll
    for (int mf = 0; mf < 4; ++mf)
#pragma unroll
      for (int nf = 0; nf < 4; ++nf)
        acc[mf][nf] = __builtin_amdgcn_mfma_f32_16x16x32_bf16(afr[mf], bfr[nf], acc[mf][nf], 0, 0, 0);

    // 4) pack A(i+1) (loaded at step i-1, long since landed) into nbuf
    if (have1) {
#pragma unroll
      for (int p = 0; p < 4; ++p) {
        u32x2 w;
        w[0] = pack_bf16x2(a1[p][0], a1[p][1]);
        w[1] = pack_bf16x2(a1[p][2], a1[p][3]);
        *reinterpret_cast<u32x2*>(&Al[nbuf][(arow + p * 32) * 32 + aoff]) = w;
      }
#pragma unroll
      for (int p = 0; p < 4; ++p) a1[p] = a2[p];
    }

    // 5) barrier with counted vmcnt: drain B(i+1) gloads + all LDS ops,
    //    leave the 4 A(i+2) loads in flight.
    if (have2) {
      asm volatile("s_waitcnt vmcnt(4) lgkmcnt(0)" ::: "memory");
    } else {
      asm volatile("s_waitcnt vmcnt(0) lgkmcnt(0)" ::: "memory");
    }
    __builtin_amdgcn_s_barrier();
    __builtin_amdgcn_sched_barrier(0);
    buf = nbuf;
  }

  // epilogue: scaled atomic accumulation (C/D: col = lane&15, row = (lane>>4)*4 + j)
  const float scale = 1.0f / (float)K_DIM;
#pragma unroll
  for (int mf = 0; mf < 4; ++mf) {
#pragma unroll
    for (int nf = 0; nf < 4; ++nf) {
      const int row = m0 + wr + mf * 16 + l16 * 4;
      const int col = n0 + wc + nf * 16 + l15;
#pragma unroll
      for (int j = 0; j < 4; ++j)
        atomicAdd(&out[(size_t)(row + j) * N_DIM + col], acc[mf][nf][j] * scale);
    }
  }
}

// ---------------------------------------------------------------------------
extern "C" void kernel_launch(void* const* d_in, const int* in_sizes, int n_in,
                              void* d_out, int out_size, void* d_ws, size_t ws_size,
                              hipStream_t stream) {
  (void)in_sizes; (void)n_in; (void)out_size; (void)ws_size;
  const float* x    = (const float*)d_in[0];
  const float* emb  = (const float*)d_in[1];
  const float* bias = (const float*)d_in[2];
  float*    out = (float*)d_out;
  uint16_t* bt  = (uint16_t*)d_ws;   // 512*20000*2 = 20.48 MB

  bt_transpose_kernel<<<dim3(K_DIM / 32, N_DIM / 64), 256, 0, stream>>>(emb, bt);
  init_out_kernel<<<(M_DIM * N_DIM) / 256, 256, 0, stream>>>(bias, out);
  gemm_split_kernel<<<GRID, GEMM_THREADS, 0, stream>>>(x, bt, out);
}